// Round 8
// baseline (461.424 us; speedup 1.0000x reference)
//
#include <hip/hip_runtime.h>
#include <hip/hip_cooperative_groups.h>

namespace cg = cooperative_groups;

// GAT layer: N=100000, E=3200000, IN=128, OUT=64.
// R16: single cooperative mega-kernel. Ledger across R10-R15: unaccounted time
//   ~= 18-25us x dispatch count (launch overhead), not any kernel -- which is
//   why R12/R13/R14 kernel micro-fixes were all nulls on total. Fuse all 5
//   phases into k_fused (391 blocks x 1024 thr, LDS union 78.8KB -> 2/CU,
//   391 <= 512 co-resident, launch_bounds(1024,8) caps VGPR<=64) with
//   grid.sync() at the 3 cross-block dependency points. Phase bodies are the
//   proven implementations; bucket phase = R13 70us body + R15 alpha-pass.
//   Non-cooperative 5-kernel fallback kept in case coop launch fails.

#define IN_DIM 128
#define OUT_DIM 64
#define MAXBKT 512       // static sizing; nbkt = ceil(n/256) = 391
#define BKN 256          // nodes per bucket
#define SEPT 8           // edges per thread in count (1024 thr)
#define SCHUNK (1024 * SEPT)    // 8192 edges per chunk -> nsb = 391
#define CAP 9216         // records per bucket window (mean 8192, sd 90)

typedef __attribute__((ext_vector_type(8))) short bf16x8;
typedef __attribute__((ext_vector_type(4))) float f32x4;

__device__ __forceinline__ unsigned short f2bf(float f) {
    unsigned u = __float_as_uint(f);
    return (unsigned short)((u + 0x7FFFu + ((u >> 16) & 1u)) >> 16);
}
__device__ __forceinline__ float bf2f(unsigned short u) {
    return __uint_as_float((unsigned)u << 16);
}
__device__ __forceinline__ float expg(float d) {
    return __expf(fmaxf(d, -80.f));
}

struct KParams {
    const float* x; const float* W; const float* a_src; const float* a_tgt;
    const int* src; const int* tgt; const float* ew;
    unsigned short* hh; float* hs; float* ht;
    int* bfill; int* histT; float2* ecoarse; float* out;
    int n, ecount, nbkt, nsb, nlb;
};

union SharedU {
    struct {   // P0 linear: split-bf16 staging (71680 B)
        unsigned short whi[64][136], wlo[64][136];
        unsigned short xhi[64][136], xlo[64][136];
        float hsp[4][64], htp[4][64];
    } lin;
    struct { int h[MAXBKT]; int base[MAXBKT]; } cs;   // P1 count / P3 scat
    struct { int lds[512]; } scan;                    // P2 colscan
    struct {   // P4 bucket (78848 B)
        float2 recs[CAP];
        int cnt[BKN], pos0[BKN], fill[BKN];
        float mf[BKN], rden[BKN];
    } bkt;
};

// ---------------- P0: h = x@W via MFMA (split bf16), hs/ht epilogue ---------
// Block handles 256 nodes in 4 sequential 64-row tiles. 16 waves: wave w owns
// (row-group w&3, nt-tile w>>2) -> 12 MFMAs each. C/D: col=l15, row=lhi*4+q
// (verified m89). hs/ht partials cross-wave-reduced via LDS; hh stored direct.
__device__ void phase_lin(const KParams& P, SharedU& su, int blk, int tid)
{
    auto& L = su.lin;
    if (blk < P.nlb) {
        const float4* W4 = (const float4*)P.W;
        #pragma unroll
        for (int j = 0; j < 2; ++j) {
            int i4 = tid + 1024 * j;
            int k = i4 >> 4, d4 = i4 & 15;
            float4 v = W4[i4];
            float vv[4] = {v.x, v.y, v.z, v.w};
            #pragma unroll
            for (int m = 0; m < 4; ++m) {
                unsigned short hi = f2bf(vv[m]);
                L.whi[d4 * 4 + m][k] = hi;
                L.wlo[d4 * 4 + m][k] = f2bf(vv[m] - bf2f(hi));
            }
        }
    }
    const int lane = tid & 63, l15 = lane & 15, lhi = lane >> 4;
    const int w = tid >> 6, rowgrp = w & 3, nt = w >> 2;
    const int arow = rowgrp * 16 + l15, kb = lhi * 8;

    for (int tt = 0; tt < 4; ++tt) {
        const int node0 = blk * 256 + tt * 64;
        const bool act = (blk < P.nlb) && (node0 < P.n);
        __syncthreads();
        if (act) {
            #pragma unroll
            for (int j = 0; j < 2; ++j) {
                int i4 = tid + 1024 * j;
                int r = i4 >> 5, c4 = i4 & 31;
                int node = node0 + r;
                float4 v = make_float4(0.f, 0.f, 0.f, 0.f);
                if (node < P.n) v = ((const float4*)(P.x + (size_t)node * IN_DIM))[c4];
                float vv[4] = {v.x, v.y, v.z, v.w};
                ushort4 ph, pl;
                unsigned short* php = (unsigned short*)&ph;
                unsigned short* plp = (unsigned short*)&pl;
                #pragma unroll
                for (int m = 0; m < 4; ++m) {
                    unsigned short hi = f2bf(vv[m]);
                    php[m] = hi;
                    plp[m] = f2bf(vv[m] - bf2f(hi));
                }
                *(ushort4*)&L.xhi[r][c4 * 4] = ph;
                *(ushort4*)&L.xlo[r][c4 * 4] = pl;
            }
        }
        __syncthreads();
        if (act) {
            f32x4 acc = (f32x4){0.f, 0.f, 0.f, 0.f};
            #pragma unroll
            for (int k0 = 0; k0 < 4; ++k0) {
                bf16x8 ahi = *(const bf16x8*)&L.xhi[arow][k0 * 32 + kb];
                bf16x8 alo = *(const bf16x8*)&L.xlo[arow][k0 * 32 + kb];
                bf16x8 bhi = *(const bf16x8*)&L.whi[nt * 16 + l15][k0 * 32 + kb];
                bf16x8 blo = *(const bf16x8*)&L.wlo[nt * 16 + l15][k0 * 32 + kb];
                acc = __builtin_amdgcn_mfma_f32_16x16x32_bf16(ahi, bhi, acc, 0, 0, 0);
                acc = __builtin_amdgcn_mfma_f32_16x16x32_bf16(ahi, blo, acc, 0, 0, 0);
                acc = __builtin_amdgcn_mfma_f32_16x16x32_bf16(alo, bhi, acc, 0, 0, 0);
            }
            float asv = P.a_src[nt * 16 + l15];
            float atv = P.a_tgt[nt * 16 + l15];
            #pragma unroll
            for (int q = 0; q < 4; ++q) {
                float ps = acc[q] * asv, pt = acc[q] * atv;
                #pragma unroll
                for (int off = 8; off; off >>= 1) {
                    ps += __shfl_xor(ps, off);
                    pt += __shfl_xor(pt, off);
                }
                int rit = rowgrp * 16 + lhi * 4 + q;
                if (l15 == 0) { L.hsp[nt][rit] = ps; L.htp[nt][rit] = pt; }
                int node = node0 + rit;
                if (node < P.n)
                    P.hh[(size_t)node * OUT_DIM + nt * 16 + l15] = f2bf(acc[q]);
            }
        }
        __syncthreads();
        if (act && tid < 64) {
            int node = node0 + tid;
            if (node < P.n) {
                P.hs[node] = L.hsp[0][tid] + L.hsp[1][tid] + L.hsp[2][tid] + L.hsp[3][tid];
                P.ht[node] = L.htp[0][tid] + L.htp[1][tid] + L.htp[2][tid] + L.htp[3][tid];
            }
        }
    }
}

// ---------------- P1: per-chunk bucket histogram ----------------------------
__device__ void phase_count(const KParams& P, SharedU& su, int blk, int tid)
{
    if (blk >= P.nsb) return;
    auto& C = su.cs;
    for (int i = tid; i < P.nbkt; i += 1024) C.h[i] = 0;
    __syncthreads();
    const int e0 = blk * SCHUNK;
    #pragma unroll
    for (int k = 0; k < SEPT; ++k) {
        int j = e0 + k * 1024 + tid;
        if (j < P.ecount) atomicAdd(&C.h[P.tgt[j] >> 8], 1);
    }
    __syncthreads();
    for (int i = tid; i < P.nbkt; i += 1024) P.histT[i * P.nsb + blk] = C.h[i];
}

// ---------------- P2: per-bucket exclusive scan of chunk counts -------------
__device__ void phase_scan(const KParams& P, SharedU& su, int blk, int tid)
{
    if (blk >= P.nbkt) return;
    int v = 0;
    if (tid < 512) {
        v = (tid < P.nsb) ? P.histT[blk * P.nsb + tid] : 0;
        su.scan.lds[tid] = v;
    }
    __syncthreads();
    for (int off = 1; off < 512; off <<= 1) {
        int u = (tid < 512 && tid >= off) ? su.scan.lds[tid - off] : 0;
        __syncthreads();
        if (tid < 512) su.scan.lds[tid] += u;
        __syncthreads();
    }
    if (tid < P.nsb) P.histT[blk * P.nsb + tid] = blk * CAP + (su.scan.lds[tid] - v);
    if (tid == 511) P.bfill[blk] = blk * CAP + su.scan.lds[511];
}

// ---------------- P3: edge logits + deterministic scatter -------------------
// Two 4-edge register batches (VGPR headroom for launch_bounds(1024,8)).
// pos = histT[bkt][blk] + LDS local rank. Zero global atomics.
__device__ void phase_scat(const KParams& P, SharedU& su, int blk, int tid)
{
    if (blk >= P.nsb) return;
    auto& C = su.cs;
    for (int i = tid; i < P.nbkt; i += 1024) {
        C.h[i] = 0;
        C.base[i] = P.histT[i * P.nsb + blk];
    }
    __syncthreads();
    const int e0 = blk * SCHUNK;
    #pragma unroll 1
    for (int half = 0; half < 2; ++half) {
        const int eh = e0 + half * 4096;
        unsigned kreg[4]; int breg[4]; float wreg[4];
        #pragma unroll
        for (int k = 0; k < 4; ++k) {
            int j = eh + k * 1024 + tid;
            bool valid = j < P.ecount;
            int s = valid ? P.src[j] : 0;
            int t = valid ? P.tgt[j] : 0;
            wreg[k] = valid ? P.ew[j] : 0.f;
            kreg[k] = ((unsigned)s << 8) | ((unsigned)t & 255u);
            breg[k] = t >> 8;
        }
        float hsr[4], htr[4];
        #pragma unroll
        for (int k = 0; k < 4; ++k) hsr[k] = P.hs[kreg[k] >> 8];
        #pragma unroll
        for (int k = 0; k < 4; ++k) htr[k] = P.ht[(breg[k] << 8) | (int)(kreg[k] & 255u)];
        int rank[4];
        #pragma unroll
        for (int k = 0; k < 4; ++k) {
            int j = eh + k * 1024 + tid;
            if (j < P.ecount) rank[k] = atomicAdd(&C.h[breg[k]], 1);
        }
        #pragma unroll
        for (int k = 0; k < 4; ++k) {
            int j = eh + k * 1024 + tid;
            if (j < P.ecount) {
                float v = hsr[k] + htr[k];
                v = (v > 0.f) ? v : 0.2f * v;      // leaky_relu slope 0.2
                v *= wreg[k];
                P.ecoarse[C.base[breg[k]] + rank[k]] =
                    make_float2(__uint_as_float(kreg[k]), v);
            }
        }
    }
}

// ---------------- P4: per-bucket sort(LDS) + softmax + aggregation ----------
// R13-proven body + R15 alpha-precompute (one exp/edge into recs[].y).
__device__ void phase_bkt(const KParams& P, SharedU& su, int blk, int tid)
{
    if (blk >= P.nbkt) return;
    auto& B = su.bkt;
    const int base  = blk * CAP;
    const int node0 = blk << 8;
    int mcnt = P.bfill[blk] - base;
    if (mcnt > CAP) mcnt = CAP;

    for (int i = tid; i < BKN; i += 1024) B.cnt[i] = 0;
    __syncthreads();

    for (int j = tid; j < mcnt; j += 1024) {
        unsigned k = __float_as_uint(P.ecoarse[base + j].x);
        atomicAdd(&B.cnt[k & 255u], 1);
    }
    __syncthreads();

    if (tid < BKN) B.pos0[tid] = B.cnt[tid];
    __syncthreads();
    for (int off = 1; off < BKN; off <<= 1) {
        int u = 0;
        if (tid < BKN && tid >= off) u = B.pos0[tid - off];
        __syncthreads();
        if (tid < BKN) B.pos0[tid] += u;
        __syncthreads();
    }
    if (tid < BKN) B.fill[tid] = B.pos0[tid] - B.cnt[tid];
    __syncthreads();
    if (tid < BKN) B.pos0[tid] = B.fill[tid];
    __syncthreads();

    for (int j = tid; j < mcnt; j += 1024) {
        float2 e = P.ecoarse[base + j];
        unsigned k = __float_as_uint(e.x);
        int p = atomicAdd(&B.fill[k & 255u], 1);
        if (p < CAP) B.recs[p] = e;
    }
    __syncthreads();

    // Phase A: per-node online softmax; 16-lane groups, 4 nodes per wave
    {
        const int G   = tid >> 4;
        const int l16 = tid & 15;
        #pragma unroll
        for (int r = 0; r < 4; ++r) {
            int tl = G + 64 * r;
            int s0 = B.pos0[tl], c = B.cnt[tl];
            float m = -INFINITY, s = 0.f;
            for (int j = l16; j < c; j += 16) {
                float v = B.recs[s0 + j].y;
                float nm = fmaxf(m, v);
                s = s * expg(m - nm) + expg(v - nm);
                m = nm;
            }
            #pragma unroll
            for (int off = 8; off; off >>= 1) {
                float mo = __shfl_xor(m, off);
                float so = __shfl_xor(s, off);
                float nm = fmaxf(m, mo);
                s = s * expg(m - nm) + so * expg(mo - nm);
                m = nm;
            }
            if (l16 == 0) { B.mf[tl] = m; B.rden[tl] = 1.f / (s + 1e-10f); }
        }
    }
    __syncthreads();

    // Alpha pass: one exp per edge, written back into recs[].y
    int ntot = B.fill[BKN - 1];
    if (ntot > CAP) ntot = CAP;
    for (int j = tid; j < ntot; j += 1024) {
        float2 e = B.recs[j];
        int tl = (int)(__float_as_uint(e.x) & 255u);
        B.recs[j].y = __expf(e.y - B.mf[tl]) * B.rden[tl];
    }
    __syncthreads();

    // Phase B: wave per node, register aggregation; alpha from recs[].y
    const int lane = tid & 63;
    const int wv   = tid >> 6;
    const int g    = lane >> 4;
    const int l4   = lane & 15;
    #pragma unroll 1
    for (int r = 0; r < 16; ++r) {
        int tl = wv + 16 * r;
        int node = node0 + tl;
        if (node >= P.n) continue;
        int s0 = B.pos0[tl], e_ = s0 + B.cnt[tl];
        float4 a0 = make_float4(0.f, 0.f, 0.f, 0.f);
        float4 a1 = make_float4(0.f, 0.f, 0.f, 0.f);
        int j = s0;
        for (; j + 8 <= e_; j += 8) {
            float2 e0 = B.recs[j + g];
            float2 e1 = B.recs[j + 4 + g];
            int sA = (int)(__float_as_uint(e0.x) >> 8);
            int sB = (int)(__float_as_uint(e1.x) >> 8);
            ushort4 u0 = ((const ushort4*)(P.hh + (size_t)sA * OUT_DIM))[l4];
            ushort4 u1 = ((const ushort4*)(P.hh + (size_t)sB * OUT_DIM))[l4];
            float c0 = e0.y, c1 = e1.y;
            a0.x += c0 * bf2f(u0.x); a0.y += c0 * bf2f(u0.y);
            a0.z += c0 * bf2f(u0.z); a0.w += c0 * bf2f(u0.w);
            a1.x += c1 * bf2f(u1.x); a1.y += c1 * bf2f(u1.y);
            a1.z += c1 * bf2f(u1.z); a1.w += c1 * bf2f(u1.w);
        }
        for (; j < e_; j += 4) {
            int jj = j + g;
            bool valid = jj < e_;
            float2 ed = B.recs[valid ? jj : (e_ - 1)];
            int sidx = (int)(__float_as_uint(ed.x) >> 8);
            ushort4 uv = ((const ushort4*)(P.hh + (size_t)sidx * OUT_DIM))[l4];
            float c = valid ? ed.y : 0.f;
            a0.x += c * bf2f(uv.x); a0.y += c * bf2f(uv.y);
            a0.z += c * bf2f(uv.z); a0.w += c * bf2f(uv.w);
        }
        a0.x += a1.x; a0.y += a1.y; a0.z += a1.z; a0.w += a1.w;
        #pragma unroll
        for (int off = 32; off >= 16; off >>= 1) {
            a0.x += __shfl_xor(a0.x, off);
            a0.y += __shfl_xor(a0.y, off);
            a0.z += __shfl_xor(a0.z, off);
            a0.w += __shfl_xor(a0.w, off);
        }
        if (g == 0)
            ((float4*)(P.out + (size_t)node * OUT_DIM))[l4] = a0;
    }
}

// ---------------- fused cooperative kernel ----------------------------------
__global__ __launch_bounds__(1024, 8) void k_fused(KParams P)
{
    __shared__ SharedU su;
    cg::grid_group grid = cg::this_grid();
    const int tid = threadIdx.x;
    const int blk = blockIdx.x;

    phase_lin(P, su, blk, tid);
    __syncthreads();
    phase_count(P, su, blk, tid);
    grid.sync();
    phase_scan(P, su, blk, tid);
    grid.sync();
    phase_scat(P, su, blk, tid);
    grid.sync();
    __syncthreads();
    phase_bkt(P, su, blk, tid);
}

// ---------------- fallback: separate kernels (non-cooperative) --------------
__global__ __launch_bounds__(1024, 8) void k_p0(KParams P) { __shared__ SharedU su; phase_lin(P, su, blockIdx.x, threadIdx.x); }
__global__ __launch_bounds__(1024, 8) void k_p1(KParams P) { __shared__ SharedU su; phase_count(P, su, blockIdx.x, threadIdx.x); }
__global__ __launch_bounds__(1024, 8) void k_p2(KParams P) { __shared__ SharedU su; phase_scan(P, su, blockIdx.x, threadIdx.x); }
__global__ __launch_bounds__(1024, 8) void k_p3(KParams P) { __shared__ SharedU su; phase_scat(P, su, blockIdx.x, threadIdx.x); }
__global__ __launch_bounds__(1024, 8) void k_p4(KParams P) { __shared__ SharedU su; phase_bkt(P, su, blockIdx.x, threadIdx.x); }

extern "C" void kernel_launch(void* const* d_in, const int* in_sizes, int n_in,
                              void* d_out, int out_size, void* d_ws, size_t ws_size,
                              hipStream_t stream) {
    const float* x     = (const float*)d_in[0];
    const int*   eidx  = (const int*)d_in[1];
    const float* ew    = (const float*)d_in[2];
    const float* W     = (const float*)d_in[3];
    const float* a_src = (const float*)d_in[4];
    const float* a_tgt = (const float*)d_in[5];
    float* out = (float*)d_out;

    const int n = in_sizes[0] / IN_DIM;          // 100000
    const int E = in_sizes[2];                   // 3200000
    const int nbkt = (n + BKN - 1) / BKN;        // 391
    const int nsb  = (E + SCHUNK - 1) / SCHUNK;  // 391
    const int nlb  = (n + 255) / 256;            // 391
    int nblk = nbkt;
    if (nsb > nblk) nblk = nsb;
    if (nlb > nblk) nblk = nlb;

    // Workspace layout (4-byte units). ~43.1 MB (< proven 52.8 MB).
    unsigned* ws = (unsigned*)d_ws;
    unsigned short* hh = (unsigned short*)ws;  ws += (size_t)n * OUT_DIM / 2;
    float* hs     = (float*)ws;          ws += n;
    float* ht     = (float*)ws;          ws += n;
    int*   bfill  = (int*)ws;            ws += MAXBKT;
    int*   histT  = (int*)ws;            ws += (size_t)nbkt * nsb;
    ws = (unsigned*)(((uintptr_t)ws + 7) & ~(uintptr_t)7);
    float2* ecoarse = (float2*)ws;       // nbkt * CAP records (fixed windows)

    KParams P;
    P.x = x; P.W = W; P.a_src = a_src; P.a_tgt = a_tgt;
    P.src = eidx; P.tgt = eidx + E; P.ew = ew;
    P.hh = hh; P.hs = hs; P.ht = ht;
    P.bfill = bfill; P.histT = histT; P.ecoarse = ecoarse; P.out = out;
    P.n = n; P.ecount = E; P.nbkt = nbkt; P.nsb = nsb; P.nlb = nlb;

    void* kargs[] = { (void*)&P };
    hipError_t err = hipLaunchCooperativeKernel(
        (const void*)k_fused, dim3(nblk), dim3(1024), kargs, 0, stream);
    if (err != hipSuccess) {
        // Fallback: sequential phase kernels (correct, pays launch overhead)
        k_p0<<<nlb,  1024, 0, stream>>>(P);
        k_p1<<<nsb,  1024, 0, stream>>>(P);
        k_p2<<<nbkt, 1024, 0, stream>>>(P);
        k_p3<<<nsb,  1024, 0, stream>>>(P);
        k_p4<<<nbkt, 1024, 0, stream>>>(P);
    }
}

// Round 9
// 265.851 us; speedup vs baseline: 1.7356x; 1.7356x over previous
//
#include <hip/hip_runtime.h>

// GAT layer: N=100000, E=3200000, IN=128, OUT=64.
// R17: revert R16 fusion (coop kernel serialized phases at 2blk/CU: 347us in-
//   kernel vs ~161us split; single-dispatch still had ~114us fixed gap =>
//   launch-overhead theory dead). Back to R14 split pipeline; fix the two 70us
//   kernels with mechanism-level changes:
//   - k_scat: 3.2M uncoalescable 8B stores = 64 L2 line-transactions per wave
//     store (R12 reg-staging and R13 atomic-removal nulls: neither changed the
//     store pattern). Now: block-local counting sort in LDS (hist+scan+LDS
//     scatter), then bucket-by-bucket coalesced emission (wave per bucket run,
//     consecutive lanes -> consecutive addresses): ~6-10x fewer store txns.
//   - k_bucket: Phase B gather-concurrency-bound (2 gathers in flight/group).
//     Now 4 in flight (16-edge inner loop) + alpha-precompute (1 exp/edge).
//   k_linear (MFMA) / k_count / k_colscan byte-identical to R14.

#define IN_DIM 128
#define OUT_DIM 64
#define MAXBKT 512       // static sizing; nbkt = ceil(n/256) = 391
#define BKN 256          // nodes per bucket
#define SEPT 8           // edges per thread in count/scatter (1024 thr)
#define SCHUNK (1024 * SEPT)    // 8192 edges per chunk -> nsb = 391
#define CAP 9216         // records per bucket window (mean 8192, sd 90)

typedef __attribute__((ext_vector_type(8))) short bf16x8;
typedef __attribute__((ext_vector_type(4))) float f32x4;

__device__ __forceinline__ unsigned short f2bf(float f) {
    unsigned u = __float_as_uint(f);
    return (unsigned short)((u + 0x7FFFu + ((u >> 16) & 1u)) >> 16);
}
__device__ __forceinline__ float bf2f(unsigned short u) {
    return __uint_as_float((unsigned)u << 16);
}
__device__ __forceinline__ float expg(float d) {
    return __expf(fmaxf(d, -80.f));
}

// ---------------- K1: h = x@W via MFMA (split bf16), hs/ht epilogue --------
__global__ __launch_bounds__(256) void k_linear(
    const float* __restrict__ x, const float* __restrict__ W,
    const float* __restrict__ a_src, const float* __restrict__ a_tgt,
    unsigned short* __restrict__ hh, float* __restrict__ hs,
    float* __restrict__ ht, int n)
{
    __shared__ unsigned short xhi[64][136];
    __shared__ unsigned short xlo[64][136];
    __shared__ unsigned short whi[64][136];
    __shared__ unsigned short wlo[64][136];
    const int tid   = threadIdx.x;
    const int node0 = blockIdx.x * 64;

    {
        const float4* W4 = (const float4*)W;
        #pragma unroll
        for (int j = 0; j < 8; ++j) {
            int i4 = tid + 256 * j;
            int k = i4 >> 4, d4 = i4 & 15;
            float4 v = W4[i4];
            float vv[4] = {v.x, v.y, v.z, v.w};
            #pragma unroll
            for (int m = 0; m < 4; ++m) {
                unsigned short hi = f2bf(vv[m]);
                whi[d4 * 4 + m][k] = hi;
                wlo[d4 * 4 + m][k] = f2bf(vv[m] - bf2f(hi));
            }
        }
    }
    {
        #pragma unroll
        for (int j = 0; j < 8; ++j) {
            int i4 = tid + 256 * j;
            int r = i4 >> 5, c4 = i4 & 31;
            int node = node0 + r;
            float4 v = make_float4(0.f, 0.f, 0.f, 0.f);
            if (node < n) v = ((const float4*)(x + (size_t)node * IN_DIM))[c4];
            float vv[4] = {v.x, v.y, v.z, v.w};
            ushort4 ph, pl;
            unsigned short* php = (unsigned short*)&ph;
            unsigned short* plp = (unsigned short*)&pl;
            #pragma unroll
            for (int m = 0; m < 4; ++m) {
                unsigned short hi = f2bf(vv[m]);
                php[m] = hi;
                plp[m] = f2bf(vv[m] - bf2f(hi));
            }
            *(ushort4*)&xhi[r][c4 * 4] = ph;
            *(ushort4*)&xlo[r][c4 * 4] = pl;
        }
    }
    __syncthreads();

    const int l15  = tid & 15;
    const int lhi  = (tid & 63) >> 4;
    const int wv   = tid >> 6;
    const int arow = wv * 16 + l15;
    const int kb   = lhi * 8;

    bf16x8 ahi[4], alo[4];
    #pragma unroll
    for (int k0 = 0; k0 < 4; ++k0) {
        ahi[k0] = *(const bf16x8*)&xhi[arow][k0 * 32 + kb];
        alo[k0] = *(const bf16x8*)&xlo[arow][k0 * 32 + kb];
    }

    f32x4 acc[4];
    #pragma unroll
    for (int ntt = 0; ntt < 4; ++ntt) acc[ntt] = (f32x4){0.f, 0.f, 0.f, 0.f};

    #pragma unroll
    for (int ntt = 0; ntt < 4; ++ntt) {
        #pragma unroll
        for (int k0 = 0; k0 < 4; ++k0) {
            bf16x8 bhi = *(const bf16x8*)&whi[ntt * 16 + l15][k0 * 32 + kb];
            bf16x8 blo = *(const bf16x8*)&wlo[ntt * 16 + l15][k0 * 32 + kb];
            acc[ntt] = __builtin_amdgcn_mfma_f32_16x16x32_bf16(ahi[k0], bhi, acc[ntt], 0, 0, 0);
            acc[ntt] = __builtin_amdgcn_mfma_f32_16x16x32_bf16(ahi[k0], blo, acc[ntt], 0, 0, 0);
            acc[ntt] = __builtin_amdgcn_mfma_f32_16x16x32_bf16(alo[k0], bhi, acc[ntt], 0, 0, 0);
        }
    }

    float asv[4], atv[4];
    #pragma unroll
    for (int ntt = 0; ntt < 4; ++ntt) {
        asv[ntt] = a_src[ntt * 16 + l15];
        atv[ntt] = a_tgt[ntt * 16 + l15];
    }
    #pragma unroll
    for (int q = 0; q < 4; ++q) {
        float ps = 0.f, pt = 0.f;
        #pragma unroll
        for (int ntt = 0; ntt < 4; ++ntt) {
            ps += acc[ntt][q] * asv[ntt];
            pt += acc[ntt][q] * atv[ntt];
        }
        #pragma unroll
        for (int off = 8; off; off >>= 1) {
            ps += __shfl_xor(ps, off);
            pt += __shfl_xor(pt, off);
        }
        int node = node0 + wv * 16 + lhi * 4 + q;
        if (l15 == 0 && node < n) { hs[node] = ps; ht[node] = pt; }
    }

    __syncthreads();
    #pragma unroll
    for (int ntt = 0; ntt < 4; ++ntt) {
        #pragma unroll
        for (int q = 0; q < 4; ++q) {
            xhi[wv * 16 + lhi * 4 + q][ntt * 16 + l15] = f2bf(acc[ntt][q]);
        }
    }
    __syncthreads();
    #pragma unroll
    for (int j = 0; j < 4; ++j) {
        int i = tid + 256 * j;
        int r = i >> 4, c4 = i & 15;
        int node = node0 + r;
        if (node < n) {
            ushort4 v = *(const ushort4*)&xhi[r][c4 * 4];
            ((ushort4*)(hh + (size_t)node * OUT_DIM))[c4] = v;
        }
    }
}

// ---------------- K2: per-chunk bucket histogram ----------------------------
__global__ __launch_bounds__(1024) void k_count(
    const int* __restrict__ tgt, int* __restrict__ histT,
    int ecount, int nbkt, int nsb)
{
    __shared__ int h[MAXBKT];
    const int tid = threadIdx.x;
    const int e0  = blockIdx.x * SCHUNK;
    for (int i = tid; i < nbkt; i += 1024) h[i] = 0;
    __syncthreads();
    #pragma unroll
    for (int k = 0; k < SEPT; ++k) {
        int j = e0 + k * 1024 + tid;
        if (j < ecount) atomicAdd(&h[tgt[j] >> 8], 1);
    }
    __syncthreads();
    for (int i = tid; i < nbkt; i += 1024) histT[i * nsb + blockIdx.x] = h[i];
}

// ---------------- K3: per-bucket exclusive scan of chunk counts -------------
__global__ __launch_bounds__(512) void k_colscan(
    int* __restrict__ histT, int* __restrict__ bfill, int nsb)
{
    __shared__ int lds[512];
    const int bkt = blockIdx.x;
    const int tid = threadIdx.x;
    int v = (tid < nsb) ? histT[bkt * nsb + tid] : 0;
    lds[tid] = v;
    __syncthreads();
    for (int off = 1; off < 512; off <<= 1) {
        int u = (tid >= off) ? lds[tid - off] : 0;
        __syncthreads();
        lds[tid] += u;
        __syncthreads();
    }
    int excl = lds[tid] - v;
    if (tid < nsb) histT[bkt * nsb + tid] = bkt * CAP + excl;
    if (tid == 511) bfill[bkt] = bkt * CAP + lds[511];
}

// ---------------- K4: logits + block-local sort + COALESCED emission --------
// 1) reg-staged coalesced loads + L2-resident hs/ht gathers, compute e.
// 2) LDS hist -> local rank. 3) LDS exclusive scan -> lstart[b].
// 4) LDS scatter recs[lstart+rank]. 5) Emission: wave w owns buckets
//    {w, w+16, ...}; lanes write the bucket's run contiguously ->
//    consecutive lanes, consecutive addresses (txn-coalesced stores).
// Record: (u32 key = (src<<8)|(t&255), float e). Zero global atomics.
__global__ __launch_bounds__(1024) void k_scat(
    const int* __restrict__ src, const int* __restrict__ tgt,
    const float* __restrict__ ew, const float* __restrict__ hs,
    const float* __restrict__ ht, const int* __restrict__ histT,
    float2* __restrict__ ecoarse, int ecount, int nbkt, int nsb)
{
    __shared__ float2 recs[SCHUNK];      // 65536 B
    __shared__ int hcnt[MAXBKT];         // counts (kept through emission)
    __shared__ int lstart[MAXBKT];       // scan buffer -> local starts
    __shared__ int gbase[MAXBKT];        // this block's global run bases
    const int tid = threadIdx.x;
    const int e0  = blockIdx.x * SCHUNK;

    for (int i = tid; i < nbkt; i += 1024) {
        hcnt[i]  = 0;
        gbase[i] = histT[i * nsb + blockIdx.x];
    }

    // 1) coalesced edge loads + gathers, all in flight; compute e
    unsigned kreg[SEPT]; int breg[SEPT]; float wreg[SEPT];
    #pragma unroll
    for (int k = 0; k < SEPT; ++k) {
        int j = e0 + k * 1024 + tid;
        bool valid = j < ecount;
        int s = valid ? src[j] : 0;
        int t = valid ? tgt[j] : 0;
        wreg[k] = valid ? ew[j] : 0.f;
        kreg[k] = ((unsigned)s << 8) | ((unsigned)t & 255u);
        breg[k] = t >> 8;
    }
    float hsr[SEPT], htr[SEPT];
    #pragma unroll
    for (int k = 0; k < SEPT; ++k) hsr[k] = hs[kreg[k] >> 8];
    #pragma unroll
    for (int k = 0; k < SEPT; ++k) htr[k] = ht[(breg[k] << 8) | (int)(kreg[k] & 255u)];
    float ereg[SEPT];
    #pragma unroll
    for (int k = 0; k < SEPT; ++k) {
        float v = hsr[k] + htr[k];
        v = (v > 0.f) ? v : 0.2f * v;          // leaky_relu slope 0.2
        ereg[k] = v * wreg[k];
    }

    __syncthreads();   // hcnt zeroed, gbase loaded

    // 2) local rank
    int rank[SEPT];
    #pragma unroll
    for (int k = 0; k < SEPT; ++k) {
        int j = e0 + k * 1024 + tid;
        if (j < ecount) rank[k] = atomicAdd(&hcnt[breg[k]], 1);
    }
    __syncthreads();

    // 3) exclusive scan of hcnt -> lstart (512-lane Hillis-Steele)
    int v = 0;
    if (tid < 512) {
        v = (tid < nbkt) ? hcnt[tid] : 0;
        lstart[tid] = v;
    }
    __syncthreads();
    for (int off = 1; off < 512; off <<= 1) {
        int u = 0;
        if (tid < 512 && tid >= off) u = lstart[tid - off];
        __syncthreads();
        if (tid < 512) lstart[tid] += u;
        __syncthreads();
    }
    if (tid < 512) lstart[tid] -= v;   // exclusive
    __syncthreads();

    // 4) LDS scatter into block-sorted order
    #pragma unroll
    for (int k = 0; k < SEPT; ++k) {
        int j = e0 + k * 1024 + tid;
        if (j < ecount)
            recs[lstart[breg[k]] + rank[k]] =
                make_float2(__uint_as_float(kreg[k]), ereg[k]);
    }
    __syncthreads();

    // 5) coalesced per-bucket emission: wave per bucket run
    const int wv   = tid >> 6;
    const int lane = tid & 63;
    for (int b = wv; b < nbkt; b += 16) {
        int st = lstart[b], c = hcnt[b], gb = gbase[b];
        for (int i = lane; i < c; i += 64)
            ecoarse[gb + i] = recs[st + i];
    }
}

// ---------------- K5: per-bucket sort(LDS) + softmax + aggregation ----------
// R13-proven body + alpha-precompute (1 exp/edge) + Phase B with 4 gathers
// in flight per 16-lane group (16-edge inner loop) to halve exposed latency.
__global__ __launch_bounds__(1024, 8) void k_bucket(
    const int* __restrict__ bfill, const float2* __restrict__ ecoarse,
    const unsigned short* __restrict__ hh, float* __restrict__ out, int n)
{
    __shared__ float2 recs[CAP];       // 73728 B
    __shared__ int   cnt[BKN];
    __shared__ int   pos0[BKN];
    __shared__ int   fill[BKN];
    __shared__ float mf[BKN];
    __shared__ float rden[BKN];

    const int tid   = threadIdx.x;
    const int bkt   = blockIdx.x;
    const int base  = bkt * CAP;
    const int node0 = bkt << 8;
    int mcnt = bfill[bkt] - base;
    if (mcnt > CAP) mcnt = CAP;

    for (int i = tid; i < BKN; i += 1024) cnt[i] = 0;
    __syncthreads();

    for (int j = tid; j < mcnt; j += 1024) {
        unsigned k = __float_as_uint(ecoarse[base + j].x);
        atomicAdd(&cnt[k & 255u], 1);
    }
    __syncthreads();

    if (tid < BKN) pos0[tid] = cnt[tid];
    __syncthreads();
    for (int off = 1; off < BKN; off <<= 1) {
        int u = 0;
        if (tid < BKN && tid >= off) u = pos0[tid - off];
        __syncthreads();
        if (tid < BKN) pos0[tid] += u;
        __syncthreads();
    }
    if (tid < BKN) fill[tid] = pos0[tid] - cnt[tid];
    __syncthreads();
    if (tid < BKN) pos0[tid] = fill[tid];
    __syncthreads();

    for (int j = tid; j < mcnt; j += 1024) {
        float2 e = ecoarse[base + j];
        unsigned k = __float_as_uint(e.x);
        int p = atomicAdd(&fill[k & 255u], 1);
        if (p < CAP) recs[p] = e;
    }
    __syncthreads();

    // Phase A: per-node online softmax; 16-lane groups, 4 nodes per wave
    {
        const int G   = tid >> 4;
        const int l16 = tid & 15;
        #pragma unroll
        for (int r = 0; r < 4; ++r) {
            int tl = G + 64 * r;
            int s0 = pos0[tl], c = cnt[tl];
            float m = -INFINITY, s = 0.f;
            for (int j = l16; j < c; j += 16) {
                float v = recs[s0 + j].y;
                float nm = fmaxf(m, v);
                s = s * expg(m - nm) + expg(v - nm);
                m = nm;
            }
            #pragma unroll
            for (int off = 8; off; off >>= 1) {
                float mo = __shfl_xor(m, off);
                float so = __shfl_xor(s, off);
                float nm = fmaxf(m, mo);
                s = s * expg(m - nm) + so * expg(mo - nm);
                m = nm;
            }
            if (l16 == 0) { mf[tl] = m; rden[tl] = 1.f / (s + 1e-10f); }
        }
    }
    __syncthreads();

    // Alpha pass: one exp per edge, written back into recs[].y
    for (int j = tid; j < mcnt; j += 1024) {
        float2 e = recs[j];
        int tl = (int)(__float_as_uint(e.x) & 255u);
        recs[j].y = __expf(e.y - mf[tl]) * rden[tl];
    }
    __syncthreads();

    // Phase B: wave per node; 4 gathers in flight per 16-lane group
    const int lane = tid & 63;
    const int wv   = tid >> 6;
    const int g    = lane >> 4;
    const int l4   = lane & 15;
    #pragma unroll 1
    for (int r = 0; r < 16; ++r) {
        int tl = wv + 16 * r;
        int node = node0 + tl;
        if (node >= n) continue;
        int s0 = pos0[tl], e_ = s0 + cnt[tl];
        float4 a0 = make_float4(0.f, 0.f, 0.f, 0.f);
        float4 a1 = make_float4(0.f, 0.f, 0.f, 0.f);
        int j = s0;
        for (; j + 16 <= e_; j += 16) {
            float2 e0 = recs[j + g];
            float2 e1 = recs[j + 4 + g];
            float2 e2 = recs[j + 8 + g];
            float2 e3 = recs[j + 12 + g];
            int sA = (int)(__float_as_uint(e0.x) >> 8);
            int sB = (int)(__float_as_uint(e1.x) >> 8);
            int sC = (int)(__float_as_uint(e2.x) >> 8);
            int sD = (int)(__float_as_uint(e3.x) >> 8);
            ushort4 u0 = ((const ushort4*)(hh + (size_t)sA * OUT_DIM))[l4];
            ushort4 u1 = ((const ushort4*)(hh + (size_t)sB * OUT_DIM))[l4];
            ushort4 u2 = ((const ushort4*)(hh + (size_t)sC * OUT_DIM))[l4];
            ushort4 u3 = ((const ushort4*)(hh + (size_t)sD * OUT_DIM))[l4];
            float c0 = e0.y, c1 = e1.y, c2 = e2.y, c3 = e3.y;
            a0.x += c0 * bf2f(u0.x); a0.y += c0 * bf2f(u0.y);
            a0.z += c0 * bf2f(u0.z); a0.w += c0 * bf2f(u0.w);
            a1.x += c1 * bf2f(u1.x); a1.y += c1 * bf2f(u1.y);
            a1.z += c1 * bf2f(u1.z); a1.w += c1 * bf2f(u1.w);
            a0.x += c2 * bf2f(u2.x); a0.y += c2 * bf2f(u2.y);
            a0.z += c2 * bf2f(u2.z); a0.w += c2 * bf2f(u2.w);
            a1.x += c3 * bf2f(u3.x); a1.y += c3 * bf2f(u3.y);
            a1.z += c3 * bf2f(u3.z); a1.w += c3 * bf2f(u3.w);
        }
        for (; j + 8 <= e_; j += 8) {
            float2 e0 = recs[j + g];
            float2 e1 = recs[j + 4 + g];
            int sA = (int)(__float_as_uint(e0.x) >> 8);
            int sB = (int)(__float_as_uint(e1.x) >> 8);
            ushort4 u0 = ((const ushort4*)(hh + (size_t)sA * OUT_DIM))[l4];
            ushort4 u1 = ((const ushort4*)(hh + (size_t)sB * OUT_DIM))[l4];
            float c0 = e0.y, c1 = e1.y;
            a0.x += c0 * bf2f(u0.x); a0.y += c0 * bf2f(u0.y);
            a0.z += c0 * bf2f(u0.z); a0.w += c0 * bf2f(u0.w);
            a1.x += c1 * bf2f(u1.x); a1.y += c1 * bf2f(u1.y);
            a1.z += c1 * bf2f(u1.z); a1.w += c1 * bf2f(u1.w);
        }
        for (; j < e_; j += 4) {
            int jj = j + g;
            bool valid = jj < e_;
            float2 ed = recs[valid ? jj : (e_ - 1)];
            int sidx = (int)(__float_as_uint(ed.x) >> 8);
            ushort4 uv = ((const ushort4*)(hh + (size_t)sidx * OUT_DIM))[l4];
            float c = valid ? ed.y : 0.f;
            a0.x += c * bf2f(uv.x); a0.y += c * bf2f(uv.y);
            a0.z += c * bf2f(uv.z); a0.w += c * bf2f(uv.w);
        }
        a0.x += a1.x; a0.y += a1.y; a0.z += a1.z; a0.w += a1.w;
        #pragma unroll
        for (int off = 32; off >= 16; off >>= 1) {
            a0.x += __shfl_xor(a0.x, off);
            a0.y += __shfl_xor(a0.y, off);
            a0.z += __shfl_xor(a0.z, off);
            a0.w += __shfl_xor(a0.w, off);
        }
        if (g == 0)
            ((float4*)(out + (size_t)node * OUT_DIM))[l4] = a0;
    }
}

extern "C" void kernel_launch(void* const* d_in, const int* in_sizes, int n_in,
                              void* d_out, int out_size, void* d_ws, size_t ws_size,
                              hipStream_t stream) {
    const float* x     = (const float*)d_in[0];
    const int*   eidx  = (const int*)d_in[1];
    const float* ew    = (const float*)d_in[2];
    const float* W     = (const float*)d_in[3];
    const float* a_src = (const float*)d_in[4];
    const float* a_tgt = (const float*)d_in[5];
    float* out = (float*)d_out;

    const int n = in_sizes[0] / IN_DIM;          // 100000
    const int E = in_sizes[2];                   // 3200000
    const int* src = eidx;
    const int* tgt = eidx + E;
    const int nbkt = (n + BKN - 1) / BKN;        // 391
    const int nsb  = (E + SCHUNK - 1) / SCHUNK;  // 391

    // Workspace layout (4-byte units). ~43.1 MB (< proven 52.8 MB).
    unsigned* ws = (unsigned*)d_ws;
    unsigned short* hh = (unsigned short*)ws;  ws += (size_t)n * OUT_DIM / 2;
    float* hs     = (float*)ws;          ws += n;
    float* ht     = (float*)ws;          ws += n;
    int*   bfill  = (int*)ws;            ws += MAXBKT;
    int*   histT  = (int*)ws;            ws += (size_t)nbkt * nsb;
    ws = (unsigned*)(((uintptr_t)ws + 7) & ~(uintptr_t)7);
    float2* ecoarse = (float2*)ws;       // nbkt * CAP records (fixed windows)

    k_linear<<<(n + 63) / 64, 256, 0, stream>>>(x, W, a_src, a_tgt, hh, hs, ht, n);
    k_count<<<nsb, 1024, 0, stream>>>(tgt, histT, E, nbkt, nsb);
    k_colscan<<<nbkt, 512, 0, stream>>>(histT, bfill, nsb);
    k_scat<<<nsb, 1024, 0, stream>>>(src, tgt, ew, hs, ht, histT, ecoarse, E, nbkt, nsb);
    k_bucket<<<nbkt, 1024, 0, stream>>>(bfill, ecoarse, hh, out, n);
}